// Round 1
// baseline (446.877 us; speedup 1.0000x reference)
//
#include <hip/hip_runtime.h>

#define B 4
#define T 2048
#define D 1024
#define H 16
#define HD 64

typedef __attribute__((ext_vector_type(8))) short bf16x8;
typedef __attribute__((ext_vector_type(4))) float f32x4;

#define MFMA(a, b, c) __builtin_amdgcn_mfma_f32_16x16x32_bf16(a, b, c, 0, 0, 0)

static __device__ __forceinline__ unsigned short f2bf(float f) {
    union { float f; unsigned u; } v; v.f = f;
    unsigned r = v.u + 0x7FFFu + ((v.u >> 16) & 1u);  // RNE
    return (unsigned short)(r >> 16);
}

// load 8 consecutive fp32 and convert to a bf16x8 fragment
static __device__ __forceinline__ bf16x8 cvt8(const float* p) {
    float4 a = *(const float4*)p;
    float4 b = *(const float4*)(p + 4);
    bf16x8 r;
    r[0] = (short)f2bf(a.x); r[1] = (short)f2bf(a.y);
    r[2] = (short)f2bf(a.z); r[3] = (short)f2bf(a.w);
    r[4] = (short)f2bf(b.x); r[5] = (short)f2bf(b.y);
    r[6] = (short)f2bf(b.z); r[7] = (short)f2bf(b.w);
    return r;
}

// ---------------- kernel 1: pack/transpose weights to bf16 ----------------
// Wqt[h][e][d], Wkt[e][d], Wvt[e][d]
__global__ __launch_bounds__(256) void pack_w(const float* __restrict__ Wq,
                                              const float* __restrict__ Wk,
                                              const float* __restrict__ Wv,
                                              unsigned short* __restrict__ Wqt,
                                              unsigned short* __restrict__ Wkt,
                                              unsigned short* __restrict__ Wvt) {
    int idx = blockIdx.x * 256 + threadIdx.x;
    const int NQ = H * HD * D;          // 1048576
    const int NK = HD * D;              // 65536
    if (idx < NQ) {
        int d = idx & (D - 1);
        int he = idx >> 10;
        int e = he & (HD - 1);
        int h = he >> 6;
        Wqt[idx] = f2bf(Wq[(h * D + d) * HD + e]);
    } else if (idx < NQ + NK) {
        int j = idx - NQ;
        int d = j & (D - 1);
        int e = j >> 10;
        Wkt[j] = f2bf(Wk[d * HD + e]);
    } else if (idx < NQ + 2 * NK) {
        int j = idx - NQ - NK;
        int d = j & (D - 1);
        int e = j >> 10;
        Wvt[j] = f2bf(Wv[d * HD + e]);
    }
}

// ---------------- kernel 2: K/V projections ----------------
// grp 0: Kb[b][t][e] bf16 (bias added). grp 1: Vt[b][e][t] bf16 (bias added).
__global__ __launch_bounds__(256) void kv_gemm(const float* __restrict__ x,
                                               const unsigned short* __restrict__ Wkt,
                                               const unsigned short* __restrict__ Wvt,
                                               const float* __restrict__ bk,
                                               const float* __restrict__ bv,
                                               unsigned short* __restrict__ Kb,
                                               unsigned short* __restrict__ Vt) {
    int grp = blockIdx.x >> 6;          // 0=K, 1=V
    int rtb = blockIdx.x & 63;
    int wave = threadIdx.x >> 6;
    int lane = threadIdx.x & 63;
    int ln = lane & 15, lk = lane >> 4;
    int rt = rtb * 4 + wave;            // 0..255
    int t0 = rt * 32;                   // global row (b*T + t)

    const unsigned short* Wt = grp ? Wvt : Wkt;
    const float* bias = grp ? bv : bk;

    f32x4 acc[2][4];
#pragma unroll
    for (int s = 0; s < 2; ++s)
#pragma unroll
        for (int e = 0; e < 4; ++e) acc[s][e] = (f32x4){0.f, 0.f, 0.f, 0.f};

    for (int d0 = 0; d0 < D; d0 += 32) {
        bf16x8 a[2];
#pragma unroll
        for (int s = 0; s < 2; ++s)
            a[s] = cvt8(x + (size_t)(t0 + s * 16 + ln) * D + d0 + lk * 8);
#pragma unroll
        for (int e = 0; e < 4; ++e) {
            bf16x8 w = *(const bf16x8*)(Wt + (size_t)(e * 16 + ln) * D + d0 + lk * 8);
#pragma unroll
            for (int s = 0; s < 2; ++s) acc[s][e] = MFMA(a[s], w, acc[s][e]);
        }
    }

#pragma unroll
    for (int s = 0; s < 2; ++s)
#pragma unroll
        for (int e = 0; e < 4; ++e)
#pragma unroll
            for (int r = 0; r < 4; ++r) {
                int trow = t0 + s * 16 + lk * 4 + r;     // global row
                int ecol = e * 16 + ln;
                float val = acc[s][e][r] + bias[ecol];
                if (grp == 0) {
                    Kb[(size_t)trow * HD + ecol] = f2bf(val);
                } else {
                    int bb = trow >> 11, tl = trow & 2047;
                    Vt[((size_t)bb * HD + ecol) * T + tl] = f2bf(val);
                }
            }
}

// ---------------- kernel 3: fused Q-proj + flash attention ----------------
__global__ __launch_bounds__(256) void attn(const float* __restrict__ x,
                                            const unsigned short* __restrict__ Wqt,
                                            const float* __restrict__ bq,
                                            const unsigned short* __restrict__ Kb,
                                            const unsigned short* __restrict__ Vt,
                                            float* __restrict__ out) {
    __shared__ __align__(16) unsigned short p_s[4][32][72];

    int blk = blockIdx.x;
    int qt = blk & 15;
    int h = (blk >> 4) & 15;
    int b = blk >> 8;
    int wave = threadIdx.x >> 6, lane = threadIdx.x & 63;
    int ln = lane & 15, lk = lane >> 4;
    int t0 = qt * 128 + wave * 32;      // local token row within batch b

    // ---- Phase 0: Q strip = x[b, t0:t0+32, :] @ Wq[h] (+bq)*scale ----
    f32x4 qacc[2][4];
#pragma unroll
    for (int s = 0; s < 2; ++s)
#pragma unroll
        for (int e = 0; e < 4; ++e) qacc[s][e] = (f32x4){0.f, 0.f, 0.f, 0.f};

    const unsigned short* Wh = Wqt + (size_t)h * HD * D;
    for (int d0 = 0; d0 < D; d0 += 32) {
        bf16x8 a[2];
#pragma unroll
        for (int s = 0; s < 2; ++s)
            a[s] = cvt8(x + ((size_t)(b * T + t0 + s * 16 + ln)) * D + d0 + lk * 8);
#pragma unroll
        for (int e = 0; e < 4; ++e) {
            bf16x8 w = *(const bf16x8*)(Wh + (size_t)(e * 16 + ln) * D + d0 + lk * 8);
#pragma unroll
            for (int s = 0; s < 2; ++s) qacc[s][e] = MFMA(a[s], w, qacc[s][e]);
        }
    }

    const float scale = 0.125f;         // 1/sqrt(64)
#pragma unroll
    for (int s = 0; s < 2; ++s)
#pragma unroll
        for (int e = 0; e < 4; ++e)
#pragma unroll
            for (int r = 0; r < 4; ++r) {
                float val = (qacc[s][e][r] + bq[h * HD + e * 16 + ln]) * scale;
                p_s[wave][s * 16 + lk * 4 + r][e * 16 + ln] = f2bf(val);
            }

    // re-read Q in A-fragment layout (same wave -> ordered by data dependence)
    bf16x8 qf[2][2];
#pragma unroll
    for (int s = 0; s < 2; ++s)
#pragma unroll
        for (int es = 0; es < 2; ++es)
            qf[s][es] = *(const bf16x8*)&p_s[wave][s * 16 + ln][es * 32 + lk * 8];

    // ---- flash state ----
    float m[2][4], l[2][4];
    f32x4 o[2][4];
#pragma unroll
    for (int s = 0; s < 2; ++s)
#pragma unroll
        for (int r = 0; r < 4; ++r) { m[s][r] = -1e30f; l[s][r] = 0.f; }
#pragma unroll
    for (int s = 0; s < 2; ++s)
#pragma unroll
        for (int e = 0; e < 4; ++e) o[s][e] = (f32x4){0.f, 0.f, 0.f, 0.f};

    const unsigned short* Kbb = Kb + (size_t)b * T * HD;
    const unsigned short* Vtb = Vt + (size_t)b * HD * T;

    for (int kt = 0; kt < T / 64; ++kt) {
        int k0 = kt * 64;

        // ---- QK^T: S[32 x 64] ----
        f32x4 sacc[2][4];
#pragma unroll
        for (int s = 0; s < 2; ++s)
#pragma unroll
            for (int j = 0; j < 4; ++j) sacc[s][j] = (f32x4){0.f, 0.f, 0.f, 0.f};

#pragma unroll
        for (int es = 0; es < 2; ++es) {
            bf16x8 kf[4];
#pragma unroll
            for (int j = 0; j < 4; ++j)
                kf[j] = *(const bf16x8*)(Kbb + (size_t)(k0 + j * 16 + ln) * HD + es * 32 + lk * 8);
#pragma unroll
            for (int s = 0; s < 2; ++s)
#pragma unroll
                for (int j = 0; j < 4; ++j)
                    sacc[s][j] = MFMA(qf[s][es], kf[j], sacc[s][j]);
        }

        // ---- online softmax ----
#pragma unroll
        for (int s = 0; s < 2; ++s) {
            float pm[4];
#pragma unroll
            for (int r = 0; r < 4; ++r) {
                float v = fmaxf(fmaxf(sacc[s][0][r], sacc[s][1][r]),
                                fmaxf(sacc[s][2][r], sacc[s][3][r]));
                pm[r] = v;
            }
#pragma unroll
            for (int off = 1; off < 16; off <<= 1)
#pragma unroll
                for (int r = 0; r < 4; ++r)
                    pm[r] = fmaxf(pm[r], __shfl_xor(pm[r], off));
#pragma unroll
            for (int r = 0; r < 4; ++r) {
                float newm = fmaxf(m[s][r], pm[r]);
                float corr = __expf(m[s][r] - newm);
                m[s][r] = newm;
                float rsum = 0.f;
#pragma unroll
                for (int j = 0; j < 4; ++j) {
                    float p = __expf(sacc[s][j][r] - newm);
                    rsum += p;
                    p_s[wave][s * 16 + lk * 4 + r][j * 16 + ln] = f2bf(p);
                }
#pragma unroll
                for (int off = 1; off < 16; off <<= 1) rsum += __shfl_xor(rsum, off);
                l[s][r] = l[s][r] * corr + rsum;
#pragma unroll
                for (int e = 0; e < 4; ++e) o[s][e][r] *= corr;
            }
        }

        // ---- PV: O += P[32 x 64] * V[64 x 64] ----
#pragma unroll
        for (int ks = 0; ks < 2; ++ks) {
            bf16x8 pa[2];
#pragma unroll
            for (int s = 0; s < 2; ++s)
                pa[s] = *(const bf16x8*)&p_s[wave][s * 16 + ln][ks * 32 + lk * 8];
            bf16x8 vf[4];
#pragma unroll
            for (int e = 0; e < 4; ++e)
                vf[e] = *(const bf16x8*)(Vtb + (size_t)(e * 16 + ln) * T + k0 + ks * 32 + lk * 8);
#pragma unroll
            for (int s = 0; s < 2; ++s)
#pragma unroll
                for (int e = 0; e < 4; ++e)
                    o[s][e] = MFMA(pa[s], vf[e], o[s][e]);
        }
    }

    // ---- epilogue: out[b][t][h*64+e] = O / l ----
#pragma unroll
    for (int s = 0; s < 2; ++s)
#pragma unroll
        for (int e = 0; e < 4; ++e)
#pragma unroll
            for (int r = 0; r < 4; ++r) {
                int trow = t0 + s * 16 + lk * 4 + r;
                out[((size_t)(b * T + trow)) * D + h * HD + e * 16 + ln] =
                    o[s][e][r] / l[s][r];
            }
}

// ---------------- launcher ----------------
extern "C" void kernel_launch(void* const* d_in, const int* in_sizes, int n_in,
                              void* d_out, int out_size, void* d_ws, size_t ws_size,
                              hipStream_t stream) {
    const float* x  = (const float*)d_in[0];
    const float* Wq = (const float*)d_in[1];
    const float* bq = (const float*)d_in[2];
    const float* Wk = (const float*)d_in[3];
    const float* bk = (const float*)d_in[4];
    const float* Wv = (const float*)d_in[5];
    const float* bv = (const float*)d_in[6];
    float* out = (float*)d_out;

    // workspace layout (bytes)
    unsigned char* ws = (unsigned char*)d_ws;
    unsigned short* Wqt = (unsigned short*)(ws);                    // 2 MB
    unsigned short* Wkt = (unsigned short*)(ws + 2097152);          // 128 KB
    unsigned short* Wvt = (unsigned short*)(ws + 2228224);          // 128 KB
    unsigned short* Kb  = (unsigned short*)(ws + 2359296);          // 1 MB
    unsigned short* Vt  = (unsigned short*)(ws + 3407872);          // 1 MB
    // total 4,456,448 bytes

    pack_w<<<4608, 256, 0, stream>>>(Wq, Wk, Wv, Wqt, Wkt, Wvt);
    kv_gemm<<<128, 256, 0, stream>>>(x, Wkt, Wvt, bk, bv, Kb, Vt);
    attn<<<1024, 256, 0, stream>>>(x, Wqt, bq, Kb, Vt, out);
}

// Round 2
// 369.450 us; speedup vs baseline: 1.2096x; 1.2096x over previous
//
#include <hip/hip_runtime.h>

#define B 4
#define T 2048
#define D 1024
#define H 16
#define HD 64

typedef __attribute__((ext_vector_type(8))) short bf16x8;
typedef __attribute__((ext_vector_type(4))) float f32x4;
typedef __attribute__((ext_vector_type(16))) float f32x16;

#define MFMA16(a, b, c) __builtin_amdgcn_mfma_f32_16x16x32_bf16(a, b, c, 0, 0, 0)
#define MFMA32(a, b, c) __builtin_amdgcn_mfma_f32_32x32x16_bf16(a, b, c, 0, 0, 0)

static __device__ __forceinline__ unsigned short f2bf(float f) {
    union { float f; unsigned u; } v; v.f = f;
    unsigned r = v.u + 0x7FFFu + ((v.u >> 16) & 1u);  // RNE
    return (unsigned short)(r >> 16);
}

static __device__ __forceinline__ bf16x8 cvt8(const float* p) {
    float4 a = *(const float4*)p;
    float4 b = *(const float4*)(p + 4);
    bf16x8 r;
    r[0] = (short)f2bf(a.x); r[1] = (short)f2bf(a.y);
    r[2] = (short)f2bf(a.z); r[3] = (short)f2bf(a.w);
    r[4] = (short)f2bf(b.x); r[5] = (short)f2bf(b.y);
    r[6] = (short)f2bf(b.z); r[7] = (short)f2bf(b.w);
    return r;
}

static __device__ __forceinline__ unsigned cvtpk(float lo, float hi) {
    unsigned r;
    asm("v_cvt_pk_bf16_f32 %0, %1, %2" : "=v"(r) : "v"(lo), "v"(hi));
    return r;
}

static __device__ __forceinline__ f32x16 zero16() {
    f32x16 z;
#pragma unroll
    for (int i = 0; i < 16; ++i) z[i] = 0.f;
    return z;
}

// ---------------- kernel 0: x fp32 -> bf16 ----------------
__global__ __launch_bounds__(256) void cvt_x(const float* __restrict__ x,
                                             unsigned short* __restrict__ xbf) {
    int idx = (blockIdx.x * 256 + threadIdx.x) * 8;   // < B*T*D = 8M
    *(bf16x8*)(xbf + idx) = cvt8(x + idx);
}

// ---------------- kernel 1: pack/transpose weights to bf16 ----------------
// Wqt[h][e][d], Wkt[e][d], Wvt[e][d]
__global__ __launch_bounds__(256) void pack_w(const float* __restrict__ Wq,
                                              const float* __restrict__ Wk,
                                              const float* __restrict__ Wv,
                                              unsigned short* __restrict__ Wqt,
                                              unsigned short* __restrict__ Wkt,
                                              unsigned short* __restrict__ Wvt) {
    int idx = blockIdx.x * 256 + threadIdx.x;
    const int NQ = H * HD * D;          // 1048576
    const int NK = HD * D;              // 65536
    if (idx < NQ) {
        int d = idx & (D - 1);
        int he = idx >> 10;
        int e = he & (HD - 1);
        int h = he >> 6;
        Wqt[idx] = f2bf(Wq[(h * D + d) * HD + e]);
    } else if (idx < NQ + NK) {
        int j = idx - NQ;
        int d = j & (D - 1);
        int e = j >> 10;
        Wkt[j] = f2bf(Wk[d * HD + e]);
    } else if (idx < NQ + 2 * NK) {
        int j = idx - NQ - NK;
        int d = j & (D - 1);
        int e = j >> 10;
        Wvt[j] = f2bf(Wv[d * HD + e]);
    }
}

// ---------------- kernel 2: K/V projections ----------------
// grp 0: Kb[b][t][e] bf16 (bias added). grp 1: Vt[b][e][t] bf16 (bias added).
__global__ __launch_bounds__(256) void kv_gemm(const unsigned short* __restrict__ xbf,
                                               const unsigned short* __restrict__ Wkt,
                                               const unsigned short* __restrict__ Wvt,
                                               const float* __restrict__ bk,
                                               const float* __restrict__ bv,
                                               unsigned short* __restrict__ Kb,
                                               unsigned short* __restrict__ Vt) {
    int grp = blockIdx.x >> 7;          // 0=K, 1=V
    int rtb = blockIdx.x & 127;
    int wave = threadIdx.x >> 6;
    int lane = threadIdx.x & 63;
    int ln = lane & 15, lk = lane >> 4;
    int rt = rtb * 4 + wave;            // 0..511
    int t0 = rt * 16;                   // global row (b*T + t)

    const unsigned short* Wt = grp ? Wvt : Wkt;
    const float* bias = grp ? bv : bk;

    f32x4 acc[4];
#pragma unroll
    for (int e = 0; e < 4; ++e) acc[e] = (f32x4){0.f, 0.f, 0.f, 0.f};

    for (int d0 = 0; d0 < D; d0 += 32) {
        bf16x8 a = *(const bf16x8*)(xbf + (size_t)(t0 + ln) * D + d0 + lk * 8);
#pragma unroll
        for (int e = 0; e < 4; ++e) {
            bf16x8 w = *(const bf16x8*)(Wt + (size_t)(e * 16 + ln) * D + d0 + lk * 8);
            acc[e] = MFMA16(a, w, acc[e]);
        }
    }

#pragma unroll
    for (int e = 0; e < 4; ++e)
#pragma unroll
        for (int r = 0; r < 4; ++r) {
            int trow = t0 + lk * 4 + r;
            int ecol = e * 16 + ln;
            float val = acc[e][r] + bias[ecol];
            if (grp == 0) {
                Kb[(size_t)trow * HD + ecol] = f2bf(val);
            } else {
                int bb = trow >> 11, tl = trow & 2047;
                Vt[((size_t)bb * HD + ecol) * T + tl] = f2bf(val);
            }
        }
}

// ---------------- kernel 3: fused Q-proj + flash attention (swapped layout) --
// S^T = K·Q^T and O^T = V^T·P^T with 32x32x16 MFMA: q = lane&31 everywhere,
// softmax reduction is register-local + one lane^32 exchange.
__global__ __launch_bounds__(256) void attn(const unsigned short* __restrict__ xbf,
                                            const unsigned short* __restrict__ Wqt,
                                            const float* __restrict__ bq,
                                            const unsigned short* __restrict__ Kb,
                                            const unsigned short* __restrict__ Vt,
                                            float* __restrict__ out) {
    __shared__ float lds_t[4][32][65];   // per-warp O transpose buffer (pad 65)

    int blk = ((blockIdx.x & 7) << 7) | (blockIdx.x >> 3);  // XCD-chunked swizzle
    int qt = blk & 15;
    int h  = (blk >> 4) & 15;
    int b  = blk >> 8;
    int wave = threadIdx.x >> 6, lane = threadIdx.x & 63;
    int l31 = lane & 31, hi = lane >> 5;
    int t0 = qt * 128 + wave * 32;      // token row within batch b

    // ---- Q^T = Wq[h]^T · X^T  (D-layout: col=q=l31, row=e=crow(r,hi)) ----
    f32x16 qacc[2] = {zero16(), zero16()};
    const unsigned short* Wh = Wqt + (size_t)h * HD * D;
    const unsigned short* xrow  = xbf + (size_t)(b * T + t0 + l31) * D + hi * 8;
    const unsigned short* wrow0 = Wh + (size_t)l31 * D + hi * 8;
    const unsigned short* wrow1 = Wh + (size_t)(32 + l31) * D + hi * 8;
    for (int dk = 0; dk < D; dk += 16) {
        bf16x8 xb = *(const bf16x8*)(xrow + dk);
        qacc[0] = MFMA32(*(const bf16x8*)(wrow0 + dk), xb, qacc[0]);
        qacc[1] = MFMA32(*(const bf16x8*)(wrow1 + dk), xb, qacc[1]);
    }

    // bias + fold scale*log2(e); S will be in log2 domain
    const float sl2 = 0.125f * 1.44269504f;
    float qv[2][16];
#pragma unroll
    for (int e0 = 0; e0 < 2; ++e0)
#pragma unroll
        for (int r = 0; r < 16; ++r) {
            int crow = (r & 3) + 8 * (r >> 2) + 4 * hi;
            qv[e0][r] = (qacc[e0][r] + bq[h * HD + e0 * 32 + crow]) * sl2;
        }

    // repack Q^T D-layout -> QK B-fragments qf[dt]: lane holds Q[q][dt*16+hi*8+j]
    bf16x8 qf[4];
#pragma unroll
    for (int dt = 0; dt < 4; ++dt) {
        int s = dt >> 1;
        int b0 = 8 * (dt & 1), b1 = b0 + 4;
        unsigned c0 = cvtpk(qv[s][b0 + 0], qv[s][b0 + 1]);
        unsigned c1 = cvtpk(qv[s][b0 + 2], qv[s][b0 + 3]);
        unsigned c2 = cvtpk(qv[s][b1 + 0], qv[s][b1 + 1]);
        unsigned c3 = cvtpk(qv[s][b1 + 2], qv[s][b1 + 3]);
        auto r02 = __builtin_amdgcn_permlane32_swap(c0, c2, false, false);
        auto r13 = __builtin_amdgcn_permlane32_swap(c1, c3, false, false);
        union { unsigned u[4]; bf16x8 v; } pu;
        pu.u[0] = r02[0]; pu.u[1] = r13[0]; pu.u[2] = r02[1]; pu.u[3] = r13[1];
        qf[dt] = pu.v;
    }

    // ---- flash loop over 64-key tiles ----
    float mrun = -1e30f, lrun = 0.f;
    f32x16 o[2] = {zero16(), zero16()};
    const unsigned short* Kbb = Kb + (size_t)b * T * HD;
    const unsigned short* Vtb = Vt + (size_t)b * HD * T;

    for (int k0 = 0; k0 < T; k0 += 64) {
        // S^T[key][q]: sacc[kt2] covers keys k0+kt2*32..+31
        f32x16 sacc[2] = {zero16(), zero16()};
#pragma unroll
        for (int dt = 0; dt < 4; ++dt) {
            bf16x8 kf0 = *(const bf16x8*)(Kbb + (size_t)(k0 + l31) * HD + dt * 16 + hi * 8);
            bf16x8 kf1 = *(const bf16x8*)(Kbb + (size_t)(k0 + 32 + l31) * HD + dt * 16 + hi * 8);
            sacc[0] = MFMA32(kf0, qf[dt], sacc[0]);
            sacc[1] = MFMA32(kf1, qf[dt], sacc[1]);
        }

        // ---- online softmax (log2 domain), register trees + lane^32 swap ----
        float mx[16];
#pragma unroll
        for (int i = 0; i < 16; ++i) mx[i] = fmaxf(sacc[0][i], sacc[1][i]);
#pragma unroll
        for (int i = 0; i < 8; ++i) mx[i] = fmaxf(mx[i], mx[i + 8]);
#pragma unroll
        for (int i = 0; i < 4; ++i) mx[i] = fmaxf(mx[i], mx[i + 4]);
        float pmax = fmaxf(fmaxf(mx[0], mx[1]), fmaxf(mx[2], mx[3]));
        pmax = fmaxf(pmax, __shfl_xor(pmax, 32));

        float newm = fmaxf(mrun, pmax);
        float corr = exp2f(mrun - newm);
        mrun = newm;

#pragma unroll
        for (int kt2 = 0; kt2 < 2; ++kt2)
#pragma unroll
            for (int r = 0; r < 16; ++r)
                sacc[kt2][r] = exp2f(sacc[kt2][r] - newm);

        float sm[16];
#pragma unroll
        for (int i = 0; i < 16; ++i) sm[i] = sacc[0][i] + sacc[1][i];
#pragma unroll
        for (int i = 0; i < 8; ++i) sm[i] += sm[i + 8];
#pragma unroll
        for (int i = 0; i < 4; ++i) sm[i] += sm[i + 4];
        float rsum = (sm[0] + sm[1]) + (sm[2] + sm[3]);
        rsum += __shfl_xor(rsum, 32);

        lrun = lrun * corr + rsum;
#pragma unroll
        for (int e0 = 0; e0 < 2; ++e0)
#pragma unroll
            for (int r = 0; r < 16; ++r) o[e0][r] *= corr;

        // ---- PV: O^T += V^T · P^T; build P^T B-frags via cvt_pk+permlane ----
#pragma unroll
        for (int ks = 0; ks < 4; ++ks) {
            int s = ks >> 1;
            int b0 = 8 * (ks & 1), b1 = b0 + 4;
            unsigned c0 = cvtpk(sacc[s][b0 + 0], sacc[s][b0 + 1]);
            unsigned c1 = cvtpk(sacc[s][b0 + 2], sacc[s][b0 + 3]);
            unsigned c2 = cvtpk(sacc[s][b1 + 0], sacc[s][b1 + 1]);
            unsigned c3 = cvtpk(sacc[s][b1 + 2], sacc[s][b1 + 3]);
            auto r02 = __builtin_amdgcn_permlane32_swap(c0, c2, false, false);
            auto r13 = __builtin_amdgcn_permlane32_swap(c1, c3, false, false);
            union { unsigned u[4]; bf16x8 v; } pu;
            pu.u[0] = r02[0]; pu.u[1] = r13[0]; pu.u[2] = r02[1]; pu.u[3] = r13[1];
            bf16x8 pa = pu.v;
            bf16x8 vf0 = *(const bf16x8*)(Vtb + (size_t)l31 * T + k0 + ks * 16 + hi * 8);
            bf16x8 vf1 = *(const bf16x8*)(Vtb + (size_t)(32 + l31) * T + k0 + ks * 16 + hi * 8);
            o[0] = MFMA32(vf0, pa, o[0]);
            o[1] = MFMA32(vf1, pa, o[1]);
        }
    }

    // ---- epilogue: O^T/l -> LDS transpose -> coalesced float4 stores ----
    float inv = 1.f / lrun;
#pragma unroll
    for (int e0 = 0; e0 < 2; ++e0)
#pragma unroll
        for (int r = 0; r < 16; ++r) {
            int crow = (r & 3) + 8 * (r >> 2) + 4 * hi;
            lds_t[wave][l31][e0 * 32 + crow] = o[e0][r] * inv;
        }
    __syncthreads();

    int rgrp = lane >> 4;
    int cg = (lane & 15) * 4;
#pragma unroll
    for (int g = 0; g < 8; ++g) {
        int row = g * 4 + rgrp;
        float4 vv;
        vv.x = lds_t[wave][row][cg + 0];
        vv.y = lds_t[wave][row][cg + 1];
        vv.z = lds_t[wave][row][cg + 2];
        vv.w = lds_t[wave][row][cg + 3];
        *(float4*)(out + (size_t)(b * T + t0 + row) * D + h * HD + cg) = vv;
    }
}

// ---------------- launcher ----------------
extern "C" void kernel_launch(void* const* d_in, const int* in_sizes, int n_in,
                              void* d_out, int out_size, void* d_ws, size_t ws_size,
                              hipStream_t stream) {
    const float* x  = (const float*)d_in[0];
    const float* Wq = (const float*)d_in[1];
    const float* bq = (const float*)d_in[2];
    const float* Wk = (const float*)d_in[3];
    const float* bk = (const float*)d_in[4];
    const float* Wv = (const float*)d_in[5];
    const float* bv = (const float*)d_in[6];
    float* out = (float*)d_out;

    // workspace layout (bytes)
    unsigned char* ws = (unsigned char*)d_ws;
    unsigned short* xbf = (unsigned short*)(ws);                  // 16,777,216
    unsigned short* Wqt = (unsigned short*)(ws + 16777216);       //  2,097,152
    unsigned short* Wkt = (unsigned short*)(ws + 18874368);       //    131,072
    unsigned short* Wvt = (unsigned short*)(ws + 19005440);       //    131,072
    unsigned short* Kb  = (unsigned short*)(ws + 19136512);       //  1,048,576
    unsigned short* Vt  = (unsigned short*)(ws + 20185088);       //  1,048,576
    // total 21,233,664 bytes

    cvt_x<<<4096, 256, 0, stream>>>(x, xbf);
    pack_w<<<4608, 256, 0, stream>>>(Wq, Wk, Wv, Wqt, Wkt, Wvt);
    kv_gemm<<<256, 256, 0, stream>>>(xbf, Wkt, Wvt, bk, bv, Kb, Vt);
    attn<<<1024, 256, 0, stream>>>(xbf, Wqt, bq, Kb, Vt, out);
}

// Round 3
// 207.434 us; speedup vs baseline: 2.1543x; 1.7810x over previous
//
#include <hip/hip_runtime.h>

#define B 4
#define T 2048
#define D 1024
#define H 16
#define HD 64
#define NKT 32   // key tiles (64 keys each) per batch

typedef __attribute__((ext_vector_type(8))) short bf16x8;
typedef __attribute__((ext_vector_type(4))) float f32x4;
typedef __attribute__((ext_vector_type(16))) float f32x16;

#define MFMA16(a, b, c) __builtin_amdgcn_mfma_f32_16x16x32_bf16(a, b, c, 0, 0, 0)
#define MFMA32(a, b, c) __builtin_amdgcn_mfma_f32_32x32x16_bf16(a, b, c, 0, 0, 0)

static __device__ __forceinline__ unsigned short f2bf(float f) {
    union { float f; unsigned u; } v; v.f = f;
    unsigned r = v.u + 0x7FFFu + ((v.u >> 16) & 1u);  // RNE
    return (unsigned short)(r >> 16);
}

static __device__ __forceinline__ bf16x8 cvt8(const float* p) {
    float4 a = *(const float4*)p;
    float4 b = *(const float4*)(p + 4);
    bf16x8 r;
    r[0] = (short)f2bf(a.x); r[1] = (short)f2bf(a.y);
    r[2] = (short)f2bf(a.z); r[3] = (short)f2bf(a.w);
    r[4] = (short)f2bf(b.x); r[5] = (short)f2bf(b.y);
    r[6] = (short)f2bf(b.z); r[7] = (short)f2bf(b.w);
    return r;
}

static __device__ __forceinline__ unsigned cvtpk(float lo, float hi) {
    unsigned r;
    asm("v_cvt_pk_bf16_f32 %0, %1, %2" : "=v"(r) : "v"(lo), "v"(hi));
    return r;
}

static __device__ __forceinline__ f32x16 zero16() {
    f32x16 z;
#pragma unroll
    for (int i = 0; i < 16; ++i) z[i] = 0.f;
    return z;
}

typedef __attribute__((address_space(1))) const unsigned char gl_u8;
typedef __attribute__((address_space(3))) unsigned char lds_u8;

// async global->LDS 16B copy; LDS dest = wave-uniform base + lane*16 (HW)
static __device__ __forceinline__ void stage16(const void* g, void* l) {
    __builtin_amdgcn_global_load_lds((gl_u8*)(unsigned long long)g,
                                     (lds_u8*)(unsigned int)(unsigned long long)l,
                                     16, 0, 0);
}

// ---------------- kernel 0: x fp32 -> bf16 ----------------
__global__ __launch_bounds__(256) void cvt_x(const float* __restrict__ x,
                                             unsigned short* __restrict__ xbf) {
    int idx = (blockIdx.x * 256 + threadIdx.x) * 8;   // < B*T*D = 8M
    *(bf16x8*)(xbf + idx) = cvt8(x + idx);
}

// ---------------- kernel 1: transpose weights to bf16 (LDS-tiled) ----------
// 18 "heads": 0..15 = Wq heads, 16 = Wk, 17 = Wv. src [D][HD] -> dst [HD][D].
__global__ __launch_bounds__(256) void pack_w(const float* __restrict__ Wq,
                                              const float* __restrict__ Wk,
                                              const float* __restrict__ Wv,
                                              unsigned short* __restrict__ Wqt,
                                              unsigned short* __restrict__ Wkt,
                                              unsigned short* __restrict__ Wvt) {
    __shared__ float tile[64][65];
    int hh = blockIdx.x >> 4, db = blockIdx.x & 15;
    const float* src;
    unsigned short* dst;
    if (hh < 16)      { src = Wq + (size_t)hh * D * HD; dst = Wqt + (size_t)hh * HD * D; }
    else if (hh == 16){ src = Wk; dst = Wkt; }
    else              { src = Wv; dst = Wvt; }
    int r = threadIdx.x >> 6, c = threadIdx.x & 63;
    int d0 = db * 64;
#pragma unroll
    for (int i = 0; i < 16; ++i)
        tile[r * 16 + i][c] = src[(size_t)(d0 + r * 16 + i) * HD + c];
    __syncthreads();
#pragma unroll
    for (int j = 0; j < 16; ++j)
        dst[(size_t)(r * 16 + j) * D + d0 + c] = f2bf(tile[c][r * 16 + j]);
}

// ---------------- kernel 2: K/V projections -> swizzled 8KB tiles ----------
// K tile (b,kt): element (row=t%64, byte c=2*e) at r*128 + (c ^ ((r&7)<<4)).
// V tile (b,kt): element (row=e,    byte c=2*(t%64)) same swizzle.
__global__ __launch_bounds__(256) void kv_gemm(const unsigned short* __restrict__ xbf,
                                               const unsigned short* __restrict__ Wkt,
                                               const unsigned short* __restrict__ Wvt,
                                               const float* __restrict__ bk,
                                               const float* __restrict__ bv,
                                               unsigned char* __restrict__ Ksw,
                                               unsigned char* __restrict__ Vsw) {
    int grp = blockIdx.x >> 7;          // 0=K, 1=V
    int rtb = blockIdx.x & 127;
    int wave = threadIdx.x >> 6;
    int lane = threadIdx.x & 63;
    int ln = lane & 15, lk = lane >> 4;
    int rt = rtb * 4 + wave;            // 0..511
    int t0 = rt * 16;                   // global row (b*T + t)

    const unsigned short* Wt = grp ? Wvt : Wkt;
    const float* bias = grp ? bv : bk;

    f32x4 acc[4];
#pragma unroll
    for (int e = 0; e < 4; ++e) acc[e] = (f32x4){0.f, 0.f, 0.f, 0.f};

    for (int d0 = 0; d0 < D; d0 += 32) {
        bf16x8 a = *(const bf16x8*)(xbf + (size_t)(t0 + ln) * D + d0 + lk * 8);
#pragma unroll
        for (int e = 0; e < 4; ++e) {
            bf16x8 w = *(const bf16x8*)(Wt + (size_t)(e * 16 + ln) * D + d0 + lk * 8);
            acc[e] = MFMA16(a, w, acc[e]);
        }
    }

#pragma unroll
    for (int e = 0; e < 4; ++e)
#pragma unroll
        for (int r = 0; r < 4; ++r) {
            int trow = t0 + lk * 4 + r;
            int ecol = e * 16 + ln;
            float val = acc[e][r] + bias[ecol];
            int bb = trow >> 11, tl = trow & 2047;
            int ktile = tl >> 6;
            size_t tbase = ((size_t)(bb * NKT + ktile)) << 13;
            if (grp == 0) {
                int rr = tl & 63, cb = 2 * ecol;
                *(unsigned short*)(Ksw + tbase + rr * 128 + (cb ^ ((rr & 7) << 4))) = f2bf(val);
            } else {
                int ko = tl & 63, cb = 2 * ko;
                *(unsigned short*)(Vsw + tbase + ecol * 128 + (cb ^ ((ecol & 7) << 4))) = f2bf(val);
            }
        }
}

// ---------------- kernel 3: fused Q-proj + flash attention ----------------
// Swapped layout (q = lane&31), LDS-staged double-buffered K/V, defer-max.
__global__ __launch_bounds__(256, 4) void attn(const unsigned short* __restrict__ xbf,
                                               const unsigned short* __restrict__ Wqt,
                                               const float* __restrict__ bq,
                                               const unsigned char* __restrict__ Ksw,
                                               const unsigned char* __restrict__ Vsw,
                                               float* __restrict__ out) {
    // staging: K0 @0, K1 @8192, V0 @16384, V1 @24576 (32KB); epilogue reuses all
    __shared__ __align__(16) unsigned char smem[33280];

    int blk = ((blockIdx.x & 7) << 7) | (blockIdx.x >> 3);  // XCD-chunked swizzle
    int qt = blk & 15;
    int h  = (blk >> 4) & 15;
    int b  = blk >> 8;
    int wave = threadIdx.x >> 6, lane = threadIdx.x & 63;
    int l31 = lane & 31, hi = lane >> 5;
    int t0 = qt * 128 + wave * 32;

    const unsigned char* Kt = Ksw + (((size_t)b * NKT) << 13);
    const unsigned char* Vt = Vsw + (((size_t)b * NKT) << 13);
    int soff = wave * 1024 + lane * 16;
    int ldsw = wave * 1024;

    auto STAGE = [&](int kt, int lk, int lv) {
        const unsigned char* gK = Kt + ((size_t)kt << 13);
        const unsigned char* gV = Vt + ((size_t)kt << 13);
        stage16(gK + soff,        smem + lk + ldsw);
        stage16(gK + 4096 + soff, smem + lk + 4096 + ldsw);
        stage16(gV + soff,        smem + lv + ldsw);
        stage16(gV + 4096 + soff, smem + lv + 4096 + ldsw);
    };

    STAGE(0, 0, 16384);   // overlaps with Q-proj below

    // ---- Q^T = Wq[h]^T · X^T  (q = l31, e = crow(r,hi)) ----
    f32x16 qacc[2] = {zero16(), zero16()};
    const unsigned short* Wh = Wqt + (size_t)h * HD * D;
    const unsigned short* xrow  = xbf + (size_t)(b * T + t0 + l31) * D + hi * 8;
    const unsigned short* wrow0 = Wh + (size_t)l31 * D + hi * 8;
    const unsigned short* wrow1 = Wh + (size_t)(32 + l31) * D + hi * 8;
    for (int dk = 0; dk < D; dk += 16) {
        bf16x8 xb = *(const bf16x8*)(xrow + dk);
        qacc[0] = MFMA32(*(const bf16x8*)(wrow0 + dk), xb, qacc[0]);
        qacc[1] = MFMA32(*(const bf16x8*)(wrow1 + dk), xb, qacc[1]);
    }

    const float sl2 = 0.125f * 1.44269504f;   // fold scale*log2(e): log2 domain
    float qv[2][16];
#pragma unroll
    for (int e0 = 0; e0 < 2; ++e0)
#pragma unroll
        for (int r = 0; r < 16; ++r) {
            int crow = (r & 3) + 8 * (r >> 2) + 4 * hi;
            qv[e0][r] = (qacc[e0][r] + bq[h * HD + e0 * 32 + crow]) * sl2;
        }

    // repack Q^T -> B-fragments qf[dt]
    bf16x8 qf[4];
#pragma unroll
    for (int dt = 0; dt < 4; ++dt) {
        int s = dt >> 1;
        int b0 = 8 * (dt & 1), b1 = b0 + 4;
        unsigned c0 = cvtpk(qv[s][b0 + 0], qv[s][b0 + 1]);
        unsigned c1 = cvtpk(qv[s][b0 + 2], qv[s][b0 + 3]);
        unsigned c2 = cvtpk(qv[s][b1 + 0], qv[s][b1 + 1]);
        unsigned c3 = cvtpk(qv[s][b1 + 2], qv[s][b1 + 3]);
        auto r02 = __builtin_amdgcn_permlane32_swap(c0, c2, false, false);
        auto r13 = __builtin_amdgcn_permlane32_swap(c1, c3, false, false);
        union { unsigned u[4]; bf16x8 v; } pu;
        pu.u[0] = r02[0]; pu.u[1] = r13[0]; pu.u[2] = r02[1]; pu.u[3] = r13[1];
        qf[dt] = pu.v;
    }

    // per-lane swizzled LDS fragment bases (all ds_reads = bp[dt] + imm)
    const unsigned char* bp[4];
    int sw = (l31 & 7) << 4;
#pragma unroll
    for (int dt = 0; dt < 4; ++dt)
        bp[dt] = smem + l31 * 128 + ((dt * 32 + hi * 16) ^ sw);

    __syncthreads();   // tile 0 staged (implicit vmcnt drain)

    float mrun = -1e30f, lrun = 0.f;
    f32x16 o[2] = {zero16(), zero16()};

    auto TILE = [&](int cur, int ck, int cv, int nxt, int nk, int nv) {
        if (nxt < NKT) STAGE(nxt, nk, nv);   // prefetch next tile (async)

        // ---- QK^T from LDS ----
        f32x16 sacc[2] = {zero16(), zero16()};
        __builtin_amdgcn_s_setprio(1);
#pragma unroll
        for (int dt = 0; dt < 4; ++dt) {
            bf16x8 kf0 = *(const bf16x8*)(bp[dt] + ck);
            bf16x8 kf1 = *(const bf16x8*)(bp[dt] + ck + 4096);
            sacc[0] = MFMA32(kf0, qf[dt], sacc[0]);
            sacc[1] = MFMA32(kf1, qf[dt], sacc[1]);
        }
        __builtin_amdgcn_s_setprio(0);

        // ---- online softmax, defer-max (log2 domain) ----
        float mx[8];
#pragma unroll
        for (int i = 0; i < 8; ++i)
            mx[i] = fmaxf(fmaxf(sacc[0][i], sacc[0][i + 8]),
                          fmaxf(sacc[1][i], sacc[1][i + 8]));
#pragma unroll
        for (int i = 0; i < 4; ++i) mx[i] = fmaxf(mx[i], mx[i + 4]);
        float pmax = fmaxf(fmaxf(mx[0], mx[1]), fmaxf(mx[2], mx[3]));
        pmax = fmaxf(pmax, __shfl_xor(pmax, 32));

        if (__any(pmax - mrun > 8.0f)) {     // rescale only when needed (T13)
            float newm = fmaxf(mrun, pmax);
            float corr = exp2f(mrun - newm);
            mrun = newm;
            lrun *= corr;
#pragma unroll
            for (int e0 = 0; e0 < 2; ++e0)
#pragma unroll
                for (int r = 0; r < 16; ++r) o[e0][r] *= corr;
        }

#pragma unroll
        for (int kt2 = 0; kt2 < 2; ++kt2)
#pragma unroll
            for (int r = 0; r < 16; ++r)
                sacc[kt2][r] = exp2f(sacc[kt2][r] - mrun);

        float sm[8];
#pragma unroll
        for (int i = 0; i < 8; ++i)
            sm[i] = (sacc[0][i] + sacc[0][i + 8]) + (sacc[1][i] + sacc[1][i + 8]);
#pragma unroll
        for (int i = 0; i < 4; ++i) sm[i] += sm[i + 4];
        float rsum = (sm[0] + sm[1]) + (sm[2] + sm[3]);
        rsum += __shfl_xor(rsum, 32);
        lrun += rsum;

        // ---- PV from LDS: per-ks {V reads, cvtpk+permlane, 2 MFMA} ----
        __builtin_amdgcn_s_setprio(1);
#pragma unroll
        for (int ks = 0; ks < 4; ++ks) {
            int s = ks >> 1;
            int b0 = 8 * (ks & 1), b1 = b0 + 4;
            bf16x8 vf0 = *(const bf16x8*)(bp[ks] + cv);
            bf16x8 vf1 = *(const bf16x8*)(bp[ks] + cv + 4096);
            unsigned c0 = cvtpk(sacc[s][b0 + 0], sacc[s][b0 + 1]);
            unsigned c1 = cvtpk(sacc[s][b0 + 2], sacc[s][b0 + 3]);
            unsigned c2 = cvtpk(sacc[s][b1 + 0], sacc[s][b1 + 1]);
            unsigned c3 = cvtpk(sacc[s][b1 + 2], sacc[s][b1 + 3]);
            auto r02 = __builtin_amdgcn_permlane32_swap(c0, c2, false, false);
            auto r13 = __builtin_amdgcn_permlane32_swap(c1, c3, false, false);
            union { unsigned u[4]; bf16x8 v; } pu;
            pu.u[0] = r02[0]; pu.u[1] = r13[0]; pu.u[2] = r02[1]; pu.u[3] = r13[1];
            o[0] = MFMA32(vf0, pu.v, o[0]);
            o[1] = MFMA32(vf1, pu.v, o[1]);
        }
        __builtin_amdgcn_s_setprio(0);

        __syncthreads();   // all waves done with cur bufs; next tile staged
    };

    for (int kt = 0; kt < NKT; kt += 2) {
        TILE(kt,     0,    16384, kt + 1, 8192, 24576);
        TILE(kt + 1, 8192, 24576, kt + 2, 0,    16384);
    }

    // ---- epilogue: O^T/l -> LDS transpose -> coalesced float4 stores ----
    float inv = 1.f / lrun;
    float (*lds_t)[32][65] = (float (*)[32][65])smem;
#pragma unroll
    for (int e0 = 0; e0 < 2; ++e0)
#pragma unroll
        for (int r = 0; r < 16; ++r) {
            int crow = (r & 3) + 8 * (r >> 2) + 4 * hi;
            lds_t[wave][l31][e0 * 32 + crow] = o[e0][r] * inv;
        }
    __syncthreads();

    int rgrp = lane >> 4;
    int cg = (lane & 15) * 4;
#pragma unroll
    for (int g = 0; g < 8; ++g) {
        int row = g * 4 + rgrp;
        float4 vv;
        vv.x = lds_t[wave][row][cg + 0];
        vv.y = lds_t[wave][row][cg + 1];
        vv.z = lds_t[wave][row][cg + 2];
        vv.w = lds_t[wave][row][cg + 3];
        *(float4*)(out + (size_t)(b * T + t0 + row) * D + h * HD + cg) = vv;
    }
}

// ---------------- launcher ----------------
extern "C" void kernel_launch(void* const* d_in, const int* in_sizes, int n_in,
                              void* d_out, int out_size, void* d_ws, size_t ws_size,
                              hipStream_t stream) {
    const float* x  = (const float*)d_in[0];
    const float* Wq = (const float*)d_in[1];
    const float* bq = (const float*)d_in[2];
    const float* Wk = (const float*)d_in[3];
    const float* bk = (const float*)d_in[4];
    const float* Wv = (const float*)d_in[5];
    const float* bv = (const float*)d_in[6];
    float* out = (float*)d_out;

    unsigned char* ws = (unsigned char*)d_ws;
    unsigned short* xbf = (unsigned short*)(ws);                  // 16,777,216
    unsigned short* Wqt = (unsigned short*)(ws + 16777216);       //  2,097,152
    unsigned short* Wkt = (unsigned short*)(ws + 18874368);       //    131,072
    unsigned short* Wvt = (unsigned short*)(ws + 19005440);       //    131,072
    unsigned char*  Ksw = ws + 19136512;                          //  1,048,576
    unsigned char*  Vsw = ws + 20185088;                          //  1,048,576
    // total 21,233,664 bytes

    cvt_x<<<4096, 256, 0, stream>>>(x, xbf);
    pack_w<<<288, 256, 0, stream>>>(Wq, Wk, Wv, Wqt, Wkt, Wvt);
    kv_gemm<<<256, 256, 0, stream>>>(xbf, Wkt, Wvt, bk, bv, Ksw, Vsw);
    attn<<<1024, 256, 0, stream>>>(xbf, Wqt, bq, Ksw, Vsw, out);
}